// Round 5
// baseline (40.151 us; speedup 1.0000x reference)
//
#include <hip/hip_runtime.h>
#include <math.h>

#define NTOK 2048
#define HID  128
#define BB   4

typedef float f32x4 __attribute__((ext_vector_type(4)));

__device__ __forceinline__ float wave_red_f(float v) {
  #pragma unroll
  for (int o = 32; o; o >>= 1) v += __shfl_down(v, o, 64);
  return v;
}
__device__ __forceinline__ double wave_red_d(double v) {
  #pragma unroll
  for (int o = 32; o; o >>= 1) v += __shfl_down(v, o, 64);
  return v;
}

// ---- Kernel A: blocks 0..255 = MLP (32 rows each, 8 rows/wave);
// ----           blocks 256..259 = per-batch threshold via separable moments.
__global__ __launch_bounds__(256) void mlp_thr_kernel(
    const float* __restrict__ pc,
    const float* __restrict__ W1, const float* __restrict__ b1,
    const float* __restrict__ W2, const float* __restrict__ b2,
    const float* __restrict__ Wd, const float* __restrict__ bd,
    const float* __restrict__ Wr, const float* __restrict__ br,
    const float* __restrict__ Wm, const float* __restrict__ bm,
    float* __restrict__ outd, float* __restrict__ outr, float* __restrict__ outm,
    float* __restrict__ thr)
{
  const int tid = threadIdx.x, wave = tid >> 6, lane = tid & 63;

  if (blockIdx.x >= 256) {
    // ---------------- threshold path (separable O(N) moments, f64) ---------
    const int b = blockIdx.x - 256;
    const float2* r = (const float2*)(pc + (size_t)b * NTOK * 2);
    double m[10];
    #pragma unroll
    for (int j = 0; j < 10; ++j) m[j] = 0.0;
    for (int i = tid; i < NTOK; i += 256) {
      const float2 c = r[i];
      const double a = c.x, bq = c.y, u = 1.0 - (double)c.x, v = 1.0 - (double)c.y;
      const double a2 = a * a, b2v = bq * bq, u2 = u * u, v2 = v * v;
      m[0] += a2;       m[1] += b2v;
      m[2] += a2 * a2;  m[3] += b2v * b2v;  m[4] += a2 * b2v;
      m[5] += u2;       m[6] += v2;
      m[7] += u2 * u2;  m[8] += v2 * v2;    m[9] += u2 * v2;
    }
    #pragma unroll
    for (int j = 0; j < 10; ++j) m[j] = wave_red_d(m[j]);
    __shared__ double sm[4][10];
    if (lane == 0) {
      #pragma unroll
      for (int j = 0; j < 10; ++j) sm[wave][j] = m[j];
    }
    __syncthreads();
    if (tid == 0) {
      double t[10];
      #pragma unroll
      for (int j = 0; j < 10; ++j)
        t[j] = sm[0][j] + sm[1][j] + sm[2][j] + sm[3][j];
      const double Sq  = t[0] * t[5] + t[1] * t[6];
      const double Sqq = t[2] * t[7] + 2.0 * t[4] * t[9] + t[3] * t[8];
      const double M = (double)NTOK * (double)NTOK;
      const double mean = Sq / M;
      double var = (Sqq - Sq * Sq / M) / (M - 1.0);
      if (var < 0.0) var = 0.0;
      double sd = sqrt(var);
      if (sd < 1e-6) sd = 1e-6;
      thr[b] = (float)(mean + 1.25 * sd);
    }
    return;
  }

  // ---------------- MLP path --------------------------------------------
  __shared__ float sW2[HID * HID];      // 64 KB
  __shared__ float sh1[4][8][HID];      // 16 KB
  for (int i = tid; i < HID * HID / 4; i += 256)
    ((float4*)sW2)[i] = ((const float4*)W2)[i];
  __syncthreads();

  const int j0 = lane, j1 = lane + 64;
  const float w10_0 = W1[j0], w11_0 = W1[HID + j0], b1_0 = b1[j0];
  const float w10_1 = W1[j1], w11_1 = W1[HID + j1], b1_1 = b1[j1];
  const float b2_0 = b2[j0], b2_1 = b2[j1];
  const float wd0 = Wd[j0], wd1 = Wd[j1];
  const float wr0 = Wr[j0], wr1 = Wr[j1];
  const float wm0 = Wm[j0], wm1 = Wm[j1];
  const float bdv = bd[0], brv = br[0], bmv = bm[0];

  const int row0 = blockIdx.x * 32 + wave * 8;    // 8 rows per wave

  // phase 1: h1 = silu(x@W1+b1) -> LDS (wave-private slab, no barrier needed)
  #pragma unroll
  for (int rr = 0; rr < 8; ++rr) {
    const float x0 = pc[(row0 + rr) * 2];
    const float x1 = pc[(row0 + rr) * 2 + 1];
    const float z0 = fmaf(x0, w10_0, fmaf(x1, w11_0, b1_0));
    const float z1 = fmaf(x0, w10_1, fmaf(x1, w11_1, b1_1));
    sh1[wave][rr][j0] = z0 / (1.f + __expf(-z0));
    sh1[wave][rr][j1] = z1 / (1.f + __expf(-z1));
  }

  // phase 2: h2 = h1 @ W2 + b2, 8 rows x 2 cols per lane, k in quads
  float a0[8], a1[8];
  #pragma unroll
  for (int rr = 0; rr < 8; ++rr) { a0[rr] = b2_0; a1[rr] = b2_1; }
  for (int kq = 0; kq < HID / 4; ++kq) {
    float4 h[8];
    #pragma unroll
    for (int rr = 0; rr < 8; ++rr)
      h[rr] = *(const float4*)&sh1[wave][rr][kq * 4];
    #pragma unroll
    for (int i = 0; i < 4; ++i) {
      const float wA = sW2[(kq * 4 + i) * HID + j0];
      const float wB = sW2[(kq * 4 + i) * HID + j1];
      #pragma unroll
      for (int rr = 0; rr < 8; ++rr) {
        const float hv = ((const float*)&h[rr])[i];
        a0[rr] = fmaf(hv, wA, a0[rr]);
        a1[rr] = fmaf(hv, wB, a1[rr]);
      }
    }
  }

  // phase 3: three 1-dim heads, wave reduce
  #pragma unroll
  for (int rr = 0; rr < 8; ++rr) {
    float dd = fmaf(a0[rr], wd0, a1[rr] * wd1);
    float rv = fmaf(a0[rr], wr0, a1[rr] * wr1);
    float mv = fmaf(a0[rr], wm0, a1[rr] * wm1);
    dd = wave_red_f(dd);
    rv = wave_red_f(rv);
    mv = wave_red_f(mv);
    if (lane == 0) {
      outd[row0 + rr] = dd + bdv;
      outr[row0 + rr] = rv + brv;
      outm[row0 + rr] = mv + bmv;
    }
  }
}

// ---- Kernel B: attn rows + diffusion_field --------------------------------
// Thread tid owns columns t = tid*4+j (j=0..3) and t = 4096+tid*4+j (as f32x4
// slots tid and tid+256), fixed across all 4 rows -> (1-r_t)*sqrt(log2e) and
// diffusion[t] live in registers. All 4 rows computed before ONE barrier;
// stores are plain (cached) f32x4, batched at the end.
__global__ __launch_bounds__(256, 4) void attn_kernel(
    const float* __restrict__ pc, const float* __restrict__ diffu,
    const float* __restrict__ thr,
    float* __restrict__ attn, float* __restrict__ dfield)
{
  const int b = blockIdx.y;
  const int tid = threadIdx.x, wave = tid >> 6, lane = tid & 63;

  const float2* __restrict__ rr  = (const float2*)(pc + (size_t)b * NTOK * 2);
  const float4* __restrict__ rr4 = (const float4*)rr;
  const float4* __restrict__ sd4 = (const float4*)(diffu + b * NTOK);

  const float C = 1.2011224f;            // sqrt(log2(e)); q' = C^2 q
  float2 u[8];
  float  sdr[8];
  #pragma unroll
  for (int i = 0; i < 2; ++i) {
    const float4 c0 = rr4[tid * 2 + i * 512];
    const float4 c1 = rr4[tid * 2 + 1 + i * 512];
    u[i * 4 + 0] = make_float2(C * (1.f - c0.x), C * (1.f - c0.y));
    u[i * 4 + 1] = make_float2(C * (1.f - c0.z), C * (1.f - c0.w));
    u[i * 4 + 2] = make_float2(C * (1.f - c1.x), C * (1.f - c1.y));
    u[i * 4 + 3] = make_float2(C * (1.f - c1.z), C * (1.f - c1.w));
    const float4 dv = sd4[tid + i * 256];
    sdr[i * 4 + 0] = dv.x; sdr[i * 4 + 1] = dv.y;
    sdr[i * 4 + 2] = dv.z; sdr[i * 4 + 3] = dv.w;
  }

  const float Ts = thr[b] * 1.442695041f;   // threshold in scaled domain
  const int s0 = blockIdx.x * 4;
  const float2 rc0 = rr[s0 + 0], rc1 = rr[s0 + 1];
  const float2 rc2 = rr[s0 + 2], rc3 = rr[s0 + 3];

  float v[4][8];
  float rsum[4] = {0.f, 0.f, 0.f, 0.f};
  float dot[4]  = {0.f, 0.f, 0.f, 0.f};

  #pragma unroll
  for (int k = 0; k < 8; ++k) {
    const float ux = u[k].x, uy = u[k].y, dk = sdr[k];
    #pragma unroll
    for (int r = 0; r < 4; ++r) {
      const float2 rc = (r == 0) ? rc0 : (r == 1) ? rc1 : (r == 2) ? rc2 : rc3;
      const float d0 = rc.x * ux;
      const float d1 = rc.y * uy;
      const float q = fmaf(d0, d0, d1 * d1);       // scaled: C^2 * dist_sq
      float val = 0.f;
      if (q <= Ts)
        val = (q > 0.f)
            ? fmaf(d0 * rsqrtf(q), 0.5f, 0.5f) * __builtin_amdgcn_exp2f(-q)
            : 1.f;
      v[r][k] = val;
      rsum[r] += val;
      dot[r] = fmaf(val, dk, dot[r]);
    }
  }

  __shared__ float red[4][4][2];
  #pragma unroll
  for (int r = 0; r < 4; ++r) {
    rsum[r] = wave_red_f(rsum[r]);
    dot[r]  = wave_red_f(dot[r]);
    if (lane == 0) { red[wave][r][0] = rsum[r]; red[wave][r][1] = dot[r]; }
  }
  __syncthreads();

  float sc[4], dtot[4];
  #pragma unroll
  for (int r = 0; r < 4; ++r) {
    const float rtot = red[0][r][0] + red[1][r][0] + red[2][r][0] + red[3][r][0];
    dtot[r] = red[0][r][1] + red[1][r][1] + red[2][r][1] + red[3][r][1];
    sc[r] = 1.f / (rtot + 1e-8f);
  }

  #pragma unroll
  for (int r = 0; r < 4; ++r) {
    f32x4* arow4 = (f32x4*)(attn + ((size_t)b * NTOK + s0 + r) * NTOK);
    #pragma unroll
    for (int i = 0; i < 2; ++i) {
      f32x4 o;
      o.x = v[r][i * 4 + 0] * sc[r]; o.y = v[r][i * 4 + 1] * sc[r];
      o.z = v[r][i * 4 + 2] * sc[r]; o.w = v[r][i * 4 + 3] * sc[r];
      arow4[tid + i * 256] = o;
    }
  }
  if (tid < 4) dfield[b * NTOK + s0 + tid] = dtot[tid] * sc[tid];
}

extern "C" void kernel_launch(void* const* d_in, const int* in_sizes, int n_in,
                              void* d_out, int out_size, void* d_ws, size_t ws_size,
                              hipStream_t stream) {
  const float* pc = (const float*)d_in[0];
  const float* W1 = (const float*)d_in[1];
  const float* b1 = (const float*)d_in[2];
  const float* W2 = (const float*)d_in[3];
  const float* b2 = (const float*)d_in[4];
  const float* Wd = (const float*)d_in[5];
  const float* bd = (const float*)d_in[6];
  const float* Wr = (const float*)d_in[7];
  const float* br = (const float*)d_in[8];
  const float* Wm = (const float*)d_in[9];
  const float* bm = (const float*)d_in[10];

  float* out    = (float*)d_out;
  float* outd   = out;                                // diffusion  [B*N]
  float* outr   = out + BB * NTOK;                    // reaction   [B*N]
  float* outm   = out + 2 * BB * NTOK;                // migration  [B*N]
  float* attn   = out + 3 * BB * NTOK;                // attn       [B*N*N]
  float* dfield = attn + (size_t)BB * NTOK * NTOK;    // diffusion_field [B*N]

  float* thr = (float*)d_ws;                          // [BB]

  hipLaunchKernelGGL(mlp_thr_kernel, dim3(256 + BB), dim3(256), 0, stream,
                     pc, W1, b1, W2, b2, Wd, bd, Wr, br, Wm, bm,
                     outd, outr, outm, thr);
  hipLaunchKernelGGL(attn_kernel, dim3(NTOK / 4, BB), dim3(256), 0, stream,
                     pc, outd, thr, attn, dfield);
}

// Round 6
// 35.096 us; speedup vs baseline: 1.1440x; 1.1440x over previous
//
#include <hip/hip_runtime.h>
#include <math.h>

#define NTOK 2048
#define HID  128
#define BB   4

typedef float f32x4 __attribute__((ext_vector_type(4)));

__device__ __forceinline__ float wave_red_f(float v) {
  #pragma unroll
  for (int o = 32; o; o >>= 1) v += __shfl_down(v, o, 64);
  return v;
}
__device__ __forceinline__ double wave_red_d(double v) {
  #pragma unroll
  for (int o = 32; o; o >>= 1) v += __shfl_down(v, o, 64);
  return v;
}

// ---- Kernel A: blocks 0..31 = MLP (256 rows each, one row per thread,
// ----           heads folded through W2: w2h[k] = sum_j W2[k][j]*Wh[j]);
// ----           blocks 32..35 = per-batch threshold via separable moments.
__global__ __launch_bounds__(256) void mlp_thr_kernel(
    const float* __restrict__ pc,
    const float* __restrict__ W1, const float* __restrict__ b1,
    const float* __restrict__ W2, const float* __restrict__ b2,
    const float* __restrict__ Wd, const float* __restrict__ bd,
    const float* __restrict__ Wr, const float* __restrict__ br,
    const float* __restrict__ Wm, const float* __restrict__ bm,
    float* __restrict__ outd, float* __restrict__ outr, float* __restrict__ outm,
    float* __restrict__ thr)
{
  const int tid = threadIdx.x;

  if (blockIdx.x >= 32) {
    // ---------------- threshold path (separable O(N) moments, f64) ---------
    const int wave = tid >> 6, lane = tid & 63;
    const int b = blockIdx.x - 32;
    const float2* r = (const float2*)(pc + (size_t)b * NTOK * 2);
    double m[10];
    #pragma unroll
    for (int j = 0; j < 10; ++j) m[j] = 0.0;
    for (int i = tid; i < NTOK; i += 256) {
      const float2 c = r[i];
      const double a = c.x, bq = c.y, u = 1.0 - (double)c.x, v = 1.0 - (double)c.y;
      const double a2 = a * a, b2v = bq * bq, u2 = u * u, v2 = v * v;
      m[0] += a2;       m[1] += b2v;
      m[2] += a2 * a2;  m[3] += b2v * b2v;  m[4] += a2 * b2v;
      m[5] += u2;       m[6] += v2;
      m[7] += u2 * u2;  m[8] += v2 * v2;    m[9] += u2 * v2;
    }
    #pragma unroll
    for (int j = 0; j < 10; ++j) m[j] = wave_red_d(m[j]);
    __shared__ double sm[4][10];
    if (lane == 0) {
      #pragma unroll
      for (int j = 0; j < 10; ++j) sm[wave][j] = m[j];
    }
    __syncthreads();
    if (tid == 0) {
      double t[10];
      #pragma unroll
      for (int j = 0; j < 10; ++j)
        t[j] = sm[0][j] + sm[1][j] + sm[2][j] + sm[3][j];
      const double Sq  = t[0] * t[5] + t[1] * t[6];
      const double Sqq = t[2] * t[7] + 2.0 * t[4] * t[9] + t[3] * t[8];
      const double M = (double)NTOK * (double)NTOK;
      const double mean = Sq / M;
      double var = (Sqq - Sq * Sq / M) / (M - 1.0);
      if (var < 0.0) var = 0.0;
      double sd = sqrt(var);
      if (sd < 1e-6) sd = 1e-6;
      thr[b] = (float)(mean + 1.25 * sd);
    }
    return;
  }

  // ---------------- MLP path --------------------------------------------
  __shared__ float fw[3][HID];   // folded head vectors  w2h[k]
  __shared__ float fc[3];        // folded consts b2@Wh + bh

  // fold: 384 length-128 dot products over 256 threads (vectorized float4)
  for (int idx = tid; idx < 3 * HID; idx += 256) {
    const int head = idx >> 7, k = idx & (HID - 1);
    const float* wh = (head == 0) ? Wd : (head == 1) ? Wr : Wm;
    const float4* w2row = (const float4*)(W2 + k * HID);
    const float4* wh4   = (const float4*)wh;
    float s = 0.f;
    #pragma unroll 4
    for (int j = 0; j < HID / 4; ++j) {
      const float4 a = w2row[j], w = wh4[j];
      s = fmaf(a.x, w.x, fmaf(a.y, w.y, fmaf(a.z, w.z, fmaf(a.w, w.w, s))));
    }
    fw[head][k] = s;
  }
  if (tid < 3) {
    const float* wh = (tid == 0) ? Wd : (tid == 1) ? Wr : Wm;
    const float bh  = (tid == 0) ? bd[0] : (tid == 1) ? br[0] : bm[0];
    const float4* b24 = (const float4*)b2;
    const float4* wh4 = (const float4*)wh;
    float s = 0.f;
    for (int j = 0; j < HID / 4; ++j) {
      const float4 a = b24[j], w = wh4[j];
      s = fmaf(a.x, w.x, fmaf(a.y, w.y, fmaf(a.z, w.z, fmaf(a.w, w.w, s))));
    }
    fc[tid] = s + bh;
  }
  __syncthreads();

  const int row = blockIdx.x * 256 + tid;       // 32*256 = 8192 rows
  const float2 c = ((const float2*)pc)[row];
  const float x0 = c.x, x1 = c.y;

  float dd = 0.f, rv = 0.f, mv = 0.f;
  #pragma unroll 4
  for (int k = 0; k < HID; ++k) {
    const float z = fmaf(x0, W1[k], fmaf(x1, W1[HID + k], b1[k]));
    const float h = z * __builtin_amdgcn_rcpf(1.f + __builtin_amdgcn_exp2f(-1.442695041f * z));
    dd = fmaf(h, fw[0][k], dd);
    rv = fmaf(h, fw[1][k], rv);
    mv = fmaf(h, fw[2][k], mv);
  }
  outd[row] = dd + fc[0];
  outr[row] = rv + fc[1];
  outm[row] = mv + fc[2];
}

// ---- Kernel B: attn rows + diffusion_field, register-resident columns -----
// Thread tid owns columns t = tid*4+j and t = 1024 + tid*4+j, fixed across
// all 4 rows -> (1-r_t)*sqrt(log2e) and diffusion[t] live in registers.
// Per-row: compute v[8] -> wave reduce -> cross-wave LDS reduce -> nt stores.
// No min-occupancy clamp: let the allocator avoid spills.
__global__ __launch_bounds__(256) void attn_kernel(
    const float* __restrict__ pc, const float* __restrict__ diffu,
    const float* __restrict__ thr,
    float* __restrict__ attn, float* __restrict__ dfield)
{
  const int b = blockIdx.y;
  const int tid = threadIdx.x, wave = tid >> 6, lane = tid & 63;

  const float2* __restrict__ rr  = (const float2*)(pc + (size_t)b * NTOK * 2);
  const float4* __restrict__ rr4 = (const float4*)rr;
  const float4* __restrict__ sd4 = (const float4*)(diffu + b * NTOK);

  const float C = 1.2011224f;              // sqrt(log2(e)); q' = log2(e)*q
  float2 u[8];
  float  sdr[8];
  #pragma unroll
  for (int i = 0; i < 2; ++i) {
    const float4 c0 = rr4[tid * 2 + i * 512];
    const float4 c1 = rr4[tid * 2 + 1 + i * 512];
    u[i * 4 + 0] = make_float2(C * (1.f - c0.x), C * (1.f - c0.y));
    u[i * 4 + 1] = make_float2(C * (1.f - c0.z), C * (1.f - c0.w));
    u[i * 4 + 2] = make_float2(C * (1.f - c1.x), C * (1.f - c1.y));
    u[i * 4 + 3] = make_float2(C * (1.f - c1.z), C * (1.f - c1.w));
    const float4 dv = sd4[tid + i * 256];
    sdr[i * 4 + 0] = dv.x; sdr[i * 4 + 1] = dv.y;
    sdr[i * 4 + 2] = dv.z; sdr[i * 4 + 3] = dv.w;
  }

  const float Ts = thr[b] * 1.442695041f;  // threshold in scaled domain
  const int s0 = blockIdx.x * 4;
  __shared__ float red[2][4][2];

  for (int rs = 0; rs < 4; ++rs) {
    const int s = s0 + rs;
    const float2 rc = rr[s];               // block-uniform
    float v[8];
    float rsum = 0.f, dot = 0.f;
    #pragma unroll
    for (int k = 0; k < 8; ++k) {
      const float d0 = rc.x * u[k].x;
      const float d1 = rc.y * u[k].y;
      const float q = fmaf(d0, d0, d1 * d1);   // = log2(e) * dist_sq
      float val = 0.f;
      if (q <= Ts)
        val = (q > 0.f)
            ? fmaf(d0 * rsqrtf(q), 0.5f, 0.5f) * __builtin_amdgcn_exp2f(-q)
            : 1.f;
      v[k] = val;
      rsum += val;
      dot = fmaf(val, sdr[k], dot);
    }
    rsum = wave_red_f(rsum);
    dot  = wave_red_f(dot);
    if (lane == 0) { red[rs & 1][wave][0] = rsum; red[rs & 1][wave][1] = dot; }
    __syncthreads();
    const float rtot = red[rs & 1][0][0] + red[rs & 1][1][0] +
                       red[rs & 1][2][0] + red[rs & 1][3][0];
    const float dtot = red[rs & 1][0][1] + red[rs & 1][1][1] +
                       red[rs & 1][2][1] + red[rs & 1][3][1];
    const float sc = 1.f / (rtot + 1e-8f);
    f32x4* arow4 = (f32x4*)(attn + ((size_t)b * NTOK + s) * NTOK);
    #pragma unroll
    for (int i = 0; i < 2; ++i) {
      f32x4 o;
      o.x = v[i * 4 + 0] * sc; o.y = v[i * 4 + 1] * sc;
      o.z = v[i * 4 + 2] * sc; o.w = v[i * 4 + 3] * sc;
      __builtin_nontemporal_store(o, arow4 + tid + i * 256);
    }
    if (tid == 0) dfield[b * NTOK + s] = dtot * sc;
  }
}

extern "C" void kernel_launch(void* const* d_in, const int* in_sizes, int n_in,
                              void* d_out, int out_size, void* d_ws, size_t ws_size,
                              hipStream_t stream) {
  const float* pc = (const float*)d_in[0];
  const float* W1 = (const float*)d_in[1];
  const float* b1 = (const float*)d_in[2];
  const float* W2 = (const float*)d_in[3];
  const float* b2 = (const float*)d_in[4];
  const float* Wd = (const float*)d_in[5];
  const float* bd = (const float*)d_in[6];
  const float* Wr = (const float*)d_in[7];
  const float* br = (const float*)d_in[8];
  const float* Wm = (const float*)d_in[9];
  const float* bm = (const float*)d_in[10];

  float* out    = (float*)d_out;
  float* outd   = out;                                // diffusion  [B*N]
  float* outr   = out + BB * NTOK;                    // reaction   [B*N]
  float* outm   = out + 2 * BB * NTOK;                // migration  [B*N]
  float* attn   = out + 3 * BB * NTOK;                // attn       [B*N*N]
  float* dfield = attn + (size_t)BB * NTOK * NTOK;    // diffusion_field [B*N]

  float* thr = (float*)d_ws;                          // [BB]

  hipLaunchKernelGGL(mlp_thr_kernel, dim3(32 + BB), dim3(256), 0, stream,
                     pc, W1, b1, W2, b2, Wd, bd, Wr, br, Wm, bm,
                     outd, outr, outm, thr);
  hipLaunchKernelGGL(attn_kernel, dim3(NTOK / 4, BB), dim3(256), 0, stream,
                     pc, outd, thr, attn, dfield);
}